// Round 19
// baseline (508.689 us; speedup 1.0000x reference)
//
#include <hip/hip_runtime.h>

// ---------------------------------------------------------------------------
// PointNet mesh GNN, fp32 — factorized gather, generalized HYBRID lane split.
//   hidden preact for edge (src,dst): u[src] - v[dst]
//     u[n] = Wa . [h_n, pos_n] + ba   (per node)
//     v[n] = Wa_pos . pos_n           (per node)
//   message m = relu(u[src]-v[dst]) @ Wb + bb ; h_out[n] = relu(max_e m)
// Nodes in DESCENDING degree order. First HK slots (heaviest ~6%) get SH
// lanes/node; light majority gets SL lanes/node (SL=2 for OUT=32 doubles
// FMA per wave-slot -> better latency tolerance). One dispatch, wave-uniform
// range branch. Butterfly max; slice write with STATIC register indices;
// v-row hoisted to registers for OUT=32 layers.
// ---------------------------------------------------------------------------

__global__ __launch_bounds__(256) void prep_kernel(
    const float* __restrict__ pos, float* __restrict__ posn, int N,
    const float* __restrict__ W1a, const float* __restrict__ W2a,
    const float* __restrict__ W3a,
    float* __restrict__ W1aT, float* __restrict__ W2aT, float* __restrict__ W3aT)
{
    int idx = blockIdx.x * blockDim.x + threadIdx.x;
    if (idx < N) {
        float x = pos[idx * 3 + 0];
        float y = pos[idx * 3 + 1];
        float z = pos[idx * 3 + 2];
        float s = fmaxf(fabsf(x) + fabsf(y) + fabsf(z), 1e-12f);
        float inv = 1.0f / s;
        posn[idx * 3 + 0] = x * inv;
        posn[idx * 3 + 1] = y * inv;
        posn[idx * 3 + 2] = z * inv;
    }
    if (blockIdx.x == 0) {
        for (int t = threadIdx.x; t < 6 * 32; t += blockDim.x) {
            int i = t / 32, k = t % 32;
            W1aT[k * 6 + i] = W1a[t];
        }
        for (int t = threadIdx.x; t < 35 * 32; t += blockDim.x) {
            int i = t / 32, k = t % 32;
            W2aT[k * 35 + i] = W2a[t];
        }
        for (int t = threadIdx.x; t < 35 * 64; t += blockDim.x) {
            int i = t / 64, k = t % 64;
            W3aT[k * 35 + i] = W3a[t];
        }
    }
}

__global__ __launch_bounds__(256) void count_kernel(
    const int* __restrict__ face, int F3, int* __restrict__ deg)
{
    int t = blockIdx.x * blockDim.x + threadIdx.x;
    if (t < F3) atomicAdd(&deg[face[t]], 2);
}

// LDS-privatized histogram of clamped degrees; 64 blocks grid-stride.
__global__ __launch_bounds__(256) void hist_kernel(
    const int* __restrict__ deg, int N, int* __restrict__ hist)
{
    __shared__ int lh[256];
    lh[threadIdx.x] = 0;
    __syncthreads();
    int stride = gridDim.x * blockDim.x;
    for (int t = blockIdx.x * blockDim.x + threadIdx.x; t < N; t += stride)
        atomicAdd(&lh[min(deg[t], 255)], 1);
    __syncthreads();
    int c = lh[threadIdx.x];
    if (c) atomicAdd(&hist[threadIdx.x], c);
}

// DESCENDING bin layout: cursor[b] = sum of hist[b'] for b' > b.
__global__ __launch_bounds__(256) void binscan_kernel(
    const int* __restrict__ hist, int* __restrict__ cursor)
{
    __shared__ int sh[256];
    int t = threadIdx.x;
    int rt = 255 - t;            // reversed position
    int v = hist[rt];
    sh[t] = v;
    __syncthreads();
    for (int off = 1; off < 256; off <<= 1) {
        int tv = (t >= off) ? sh[t - off] : 0;
        __syncthreads();
        sh[t] += tv;
        __syncthreads();
    }
    cursor[rt] = sh[t] - v;      // exclusive prefix in reversed order
}

// LDS-privatized counting-sort scatter.
__global__ __launch_bounds__(256) void scatter_kernel(
    const int* __restrict__ deg, int N, int* __restrict__ cursor,
    int* __restrict__ perm)
{
    __shared__ int lh[256];
    __shared__ int lbase[256];
    int tid = threadIdx.x;
    lh[tid] = 0;
    __syncthreads();
    int t = blockIdx.x * blockDim.x + tid;
    int b = 0, r = 0;
    bool valid = (t < N);
    if (valid) {
        b = min(deg[t], 255);
        r = atomicAdd(&lh[b], 1);
    }
    __syncthreads();
    int c = lh[tid];
    if (c) lbase[tid] = atomicAdd(&cursor[tid], c);
    __syncthreads();
    if (valid) perm[lbase[b] + r] = t;
}

// ---- 3-phase multi-block exclusive scan of deg -> indptr (+ ecur copy) ----
__global__ __launch_bounds__(256) void scan_reduce(
    const int* __restrict__ val, int N, int* __restrict__ partial)
{
    __shared__ int sh[256];
    int b0 = blockIdx.x * 1024;
    int sum = 0;
    #pragma unroll
    for (int j = 0; j < 4; j++) {
        int idx = b0 + j * 256 + threadIdx.x;
        if (idx < N) sum += val[idx];
    }
    sh[threadIdx.x] = sum;
    __syncthreads();
    for (int off = 128; off > 0; off >>= 1) {
        if (threadIdx.x < off) sh[threadIdx.x] += sh[threadIdx.x + off];
        __syncthreads();
    }
    if (threadIdx.x == 0) partial[blockIdx.x] = sh[0];
}

__global__ __launch_bounds__(1024) void scan_partials(
    int* __restrict__ partial, int B, int* __restrict__ totalp)
{
    __shared__ int sh[1024];
    int t = threadIdx.x;
    int v = (t < B) ? partial[t] : 0;
    sh[t] = v;
    __syncthreads();
    for (int off = 1; off < 1024; off <<= 1) {
        int tv = (t >= off) ? sh[t - off] : 0;
        __syncthreads();
        sh[t] += tv;
        __syncthreads();
    }
    if (t < B) partial[t] = sh[t] - v;   // exclusive
    if (t == 1023) *totalp = sh[1023];
}

__global__ __launch_bounds__(256) void scan_apply(
    const int* __restrict__ val, int N, const int* __restrict__ partial,
    int* __restrict__ out1, int* __restrict__ out2)
{
    __shared__ int sh[256];
    int t = threadIdx.x;
    int i0 = blockIdx.x * 1024 + t * 4;
    int d[4];
    int s = 0;
    #pragma unroll
    for (int j = 0; j < 4; j++) {
        d[j] = (i0 + j < N) ? val[i0 + j] : 0;
        s += d[j];
    }
    sh[t] = s;
    __syncthreads();
    for (int off = 1; off < 256; off <<= 1) {
        int tv = (t >= off) ? sh[t - off] : 0;
        __syncthreads();
        sh[t] += tv;
        __syncthreads();
    }
    int run = partial[blockIdx.x] + sh[t] - s;
    #pragma unroll
    for (int j = 0; j < 4; j++) {
        int idx = i0 + j;
        if (idx < N) {
            out1[idx] = run;
            out2[idx] = run;
        }
        run += d[j];
    }
}

__global__ __launch_bounds__(256) void fill_kernel(
    const int* __restrict__ face, int F, int* __restrict__ cursor,
    int* __restrict__ srcids)
{
    int t = blockIdx.x * blockDim.x + threadIdx.x;
    if (t >= 3 * F) return;
    int r = t / F;
    int f = t - r * F;
    int v = face[t];
    int r1 = r + 1; if (r1 == 3) r1 = 0;
    int r2 = r + 2; if (r2 >= 3) r2 -= 3;
    int a = face[r1 * F + f];
    int b = face[r2 * F + f];
    int base = atomicAdd(&cursor[v], 2);
    srcids[base] = a;
    srcids[base + 1] = b;
}

// Per node: u[n][k] = ba[k] + sum_i [h_n,pos_n][i] * WaT[k][i]
//           v[n][k] = sum_c pos_n[c] * WaT[k][INH+c]
template <int INH, int OUT>
__global__ __launch_bounds__(256) void uv_kernel(
    const float* __restrict__ h, const float* __restrict__ posn,
    const float* __restrict__ WaT, const float* __restrict__ ba,
    float* __restrict__ u, float* __restrict__ v, int N)
{
    constexpr int IN = INH + 3;
    int n = blockIdx.x * blockDim.x + threadIdx.x;
    if (n >= N) return;
    float x[IN];
    if constexpr (INH % 4 == 0) {
        const float4* hp = (const float4*)(h + (size_t)n * INH);
        #pragma unroll
        for (int i4 = 0; i4 < INH / 4; i4++) {
            float4 t = hp[i4];
            x[i4 * 4 + 0] = t.x;
            x[i4 * 4 + 1] = t.y;
            x[i4 * 4 + 2] = t.z;
            x[i4 * 4 + 3] = t.w;
        }
    } else {
        #pragma unroll
        for (int i = 0; i < INH; i++) x[i] = h[(size_t)n * INH + i];
    }
    x[INH + 0] = posn[n * 3 + 0];
    x[INH + 1] = posn[n * 3 + 1];
    x[INH + 2] = posn[n * 3 + 2];

    float4* up = (float4*)(u + (size_t)n * OUT);
    float4* vp = (float4*)(v + (size_t)n * OUT);
    #pragma unroll 2
    for (int k4 = 0; k4 < OUT / 4; k4++) {
        float uu[4], vv[4];
        #pragma unroll
        for (int j = 0; j < 4; j++) {
            int k = k4 * 4 + j;
            float uk = ba[k];
            #pragma unroll
            for (int i = 0; i < IN; i++)
                uk = fmaf(x[i], WaT[k * IN + i], uk);
            uu[j] = uk;
            float vk = x[INH] * WaT[k * IN + INH];
            vk = fmaf(x[INH + 1], WaT[k * IN + INH + 1], vk);
            vk = fmaf(x[INH + 2], WaT[k * IN + INH + 2], vk);
            vv[j] = vk;
        }
        float4 u4; u4.x = uu[0]; u4.y = uu[1]; u4.z = uu[2]; u4.w = uu[3];
        float4 v4; v4.x = vv[0]; v4.y = vv[1]; v4.z = vv[2]; v4.w = vv[3];
        up[k4] = u4;
        vp[k4] = v4;
    }
}

// Shared gather body: SPLIT lanes cooperate on node perm[gslot]; full acc/M
// rows in registers (static indices); butterfly max; slice write.
template <int OUT, int SPLIT, bool VH>
__device__ __forceinline__ void gather_body(
    int gslot, int t,
    const float* __restrict__ u, const float* __restrict__ v,
    const int* __restrict__ perm, const int* __restrict__ indptr,
    const int* __restrict__ srcids, const float* __restrict__ Wb,
    const float* __restrict__ bb, float* __restrict__ hout)
{
    static_assert(SPLIT == 2 || SPLIT == 4 || SPLIT == 8, "");
    int n = perm[gslot];
    const float4* vp = (const float4*)(v + (size_t)n * OUT);
    int e0 = indptr[n], e1 = indptr[n + 1];

    float vq[VH ? OUT : 1];
    if constexpr (VH) {
        #pragma unroll
        for (int m = 0; m < OUT / 4; m++) {
            float4 x = vp[m];
            vq[4 * m + 0] = x.x;
            vq[4 * m + 1] = x.y;
            vq[4 * m + 2] = x.z;
            vq[4 * m + 3] = x.w;
        }
    }

    float M[OUT];
    #pragma unroll
    for (int o = 0; o < OUT; o++) M[o] = -1e30f;

    for (int e = e0 + t; e < e1; e += SPLIT) {
        int src = srcids[e];
        const float4* up = (const float4*)(u + (size_t)src * OUT);
        float acc[OUT];
        #pragma unroll
        for (int o = 0; o < OUT; o++) acc[o] = 0.0f;
        #pragma unroll 4
        for (int k4 = 0; k4 < OUT / 4; k4++) {
            float4 u4 = up[k4];
            float vx, vy, vz, vw;
            if constexpr (VH) {
                vx = vq[k4 * 4 + 0]; vy = vq[k4 * 4 + 1];
                vz = vq[k4 * 4 + 2]; vw = vq[k4 * 4 + 3];
            } else {
                float4 v4 = vp[k4];
                vx = v4.x; vy = v4.y; vz = v4.z; vw = v4.w;
            }
            float hk;
            hk = fmaxf(u4.x - vx, 0.0f);
            #pragma unroll
            for (int o = 0; o < OUT; o++)
                acc[o] = fmaf(hk, Wb[(k4 * 4 + 0) * OUT + o], acc[o]);
            hk = fmaxf(u4.y - vy, 0.0f);
            #pragma unroll
            for (int o = 0; o < OUT; o++)
                acc[o] = fmaf(hk, Wb[(k4 * 4 + 1) * OUT + o], acc[o]);
            hk = fmaxf(u4.z - vz, 0.0f);
            #pragma unroll
            for (int o = 0; o < OUT; o++)
                acc[o] = fmaf(hk, Wb[(k4 * 4 + 2) * OUT + o], acc[o]);
            hk = fmaxf(u4.w - vw, 0.0f);
            #pragma unroll
            for (int o = 0; o < OUT; o++)
                acc[o] = fmaf(hk, Wb[(k4 * 4 + 3) * OUT + o], acc[o]);
        }
        #pragma unroll
        for (int o = 0; o < OUT; o++) M[o] = fmaxf(M[o], acc[o]);
    }

    // butterfly max across the aligned SPLIT-lane group (static indices)
    #pragma unroll
    for (int m = 1; m < SPLIT; m <<= 1) {
        #pragma unroll
        for (int o = 0; o < OUT; o++)
            M[o] = fmaxf(M[o], __shfl_xor(M[o], m));
    }

    // lane t writes slice t — statically unrolled branch keeps M in regs
    constexpr int CH = OUT / SPLIT;
    #pragma unroll
    for (int tt = 0; tt < SPLIT; tt++) {
        if (t == tt) {
            float* outp = hout + (size_t)n * OUT + tt * CH;
            #pragma unroll
            for (int o4 = 0; o4 < CH / 4; o4++) {
                float4 w;
                w.x = fmaxf(M[tt * CH + o4 * 4 + 0] + bb[tt * CH + o4 * 4 + 0], 0.0f);
                w.y = fmaxf(M[tt * CH + o4 * 4 + 1] + bb[tt * CH + o4 * 4 + 1], 0.0f);
                w.z = fmaxf(M[tt * CH + o4 * 4 + 2] + bb[tt * CH + o4 * 4 + 2], 0.0f);
                w.w = fmaxf(M[tt * CH + o4 * 4 + 3] + bb[tt * CH + o4 * 4 + 3], 0.0f);
                ((float4*)outp)[o4] = w;
            }
        }
    }
}

// Hybrid: first HK slots (heaviest, perm sorted desc) use SH lanes/node;
// rest use SL. HK multiple of 16 -> range boundary is 64-aligned for all
// SH in {2,4,8}, keeping the branch wave-uniform and groups wave-local.
template <int OUT, int SH, int SL, int MINW, bool VH>
__global__ __launch_bounds__(256, MINW) void gather_kernel(
    const float* __restrict__ u, const float* __restrict__ v,
    const int* __restrict__ perm, const int* __restrict__ indptr,
    const int* __restrict__ srcids, const float* __restrict__ Wb,
    const float* __restrict__ bb, float* __restrict__ hout, int N, int HK)
{
    int gt = blockIdx.x * blockDim.x + threadIdx.x;
    int hthreads = HK * SH;
    if (gt < hthreads) {
        int gslot = gt / SH;
        int t = gt % SH;
        gather_body<OUT, SH, VH>(gslot, t, u, v, perm, indptr, srcids, Wb, bb, hout);
    } else {
        int g2 = gt - hthreads;
        int gslot = HK + g2 / SL;
        int t = g2 % SL;
        if (gslot >= N) return;
        gather_body<OUT, SL, VH>(gslot, t, u, v, perm, indptr, srcids, Wb, bb, hout);
    }
}

// Global max pool over sorted batch ids (h3 >= 0, g init 0).
__global__ __launch_bounds__(256) void pool_kernel(
    const float* __restrict__ h3, const int* __restrict__ batch, int N,
    float* __restrict__ g)
{
    int o = threadIdx.x & 63;
    int sub = threadIdx.x >> 6;
    int n0 = blockIdx.x * 256;
    int nend = min(n0 + 256, N);
    int cur = -1;
    float run = 0.0f;
    for (int n = n0 + sub; n < nend; n += 4) {
        int b = batch[n];
        if (b != cur) {
            if (cur >= 0) atomicMax((int*)&g[cur * 64 + o], __float_as_int(run));
            cur = b;
            run = 0.0f;
        }
        run = fmaxf(run, h3[(size_t)n * 64 + o]);
    }
    if (cur >= 0) atomicMax((int*)&g[cur * 64 + o], __float_as_int(run));
}

__global__ __launch_bounds__(256) void head_kernel(
    const float* __restrict__ g, const float* __restrict__ Wc,
    const float* __restrict__ bc, float* __restrict__ out)
{
    int idx = blockIdx.x * blockDim.x + threadIdx.x;
    if (idx >= 64 * 41) return;
    int bg = idx / 41;
    int o = idx - bg * 41;
    float acc = bc[o];
    #pragma unroll 8
    for (int k = 0; k < 64; k++)
        acc = fmaf(g[bg * 64 + k], Wc[k * 41 + o], acc);
    out[idx] = acc;
}

extern "C" void kernel_launch(void* const* d_in, const int* in_sizes, int n_in,
                              void* d_out, int out_size, void* d_ws, size_t ws_size,
                              hipStream_t stream)
{
    const float* pos   = (const float*)d_in[0];
    const int*   batch = (const int*)d_in[1];
    const int*   face  = (const int*)d_in[2];
    const float* W1a = (const float*)d_in[3];
    const float* b1a = (const float*)d_in[4];
    const float* W1b = (const float*)d_in[5];
    const float* b1b = (const float*)d_in[6];
    const float* W2a = (const float*)d_in[7];
    const float* b2a = (const float*)d_in[8];
    const float* W2b = (const float*)d_in[9];
    const float* b2b = (const float*)d_in[10];
    const float* W3a = (const float*)d_in[11];
    const float* b3a = (const float*)d_in[12];
    const float* W3b = (const float*)d_in[13];
    const float* b3b = (const float*)d_in[14];
    const float* Wc  = (const float*)d_in[15];
    const float* bc  = (const float*)d_in[16];

    int N = in_sizes[0] / 3;
    int F = in_sizes[2] / 3;
    int F3 = 3 * F;

    float* ws   = (float*)d_ws;
    float* posn = ws;
    float* W1aT = posn + (size_t)N * 3;
    float* W2aT = W1aT + 6 * 32;
    float* W3aT = W2aT + 35 * 32;
    float* h3   = W3aT + 35 * 64;           // 64N floats; h1 aliases first 32N
    float* h1   = h3;                        // dead before gather3 writes h3
    float* h2   = h3 + (size_t)N * 64;       // 32N
    float* u    = h2 + (size_t)N * 32;       // 64N
    float* v    = u + (size_t)N * 64;        // 64N
    float* g    = v + (size_t)N * 64;        // 4096
    int* deg    = (int*)(g + 64 * 64);       // N (read-only after count)
    int* indptr = deg + N;                   // N+1
    int* srcids = indptr + (N + 1);          // 6F
    int* perm   = srcids + (size_t)6 * F;    // N
    int* hist   = perm + N;                  // 256
    int* cursor = hist + 256;                // 256
    int* ecur   = cursor + 256;              // N (fill cursor)
    int* partial = ecur + N;                 // ceil(N/1024)

    hipMemsetAsync(deg, 0, (size_t)N * sizeof(int), stream);
    hipMemsetAsync(hist, 0, 256 * sizeof(int), stream);
    hipMemsetAsync(g, 0, 64 * 64 * sizeof(float), stream);

    prep_kernel<<<(N + 255) / 256, 256, 0, stream>>>(
        pos, posn, N, W1a, W2a, W3a, W1aT, W2aT, W3aT);

    int gN = (N + 255) / 256;
    int B = (N + 1023) / 1024;
    int HK = ((N / 16) + 15) & ~15;          // heavy slot count, 16-aligned
    if (HK > N) HK = N & ~15;
    size_t t12 = (size_t)HK * 4 + (size_t)(N - HK) * 2;
    size_t t3  = (size_t)HK * 8 + (size_t)(N - HK) * 4;
    int g12 = (int)((t12 + 255) / 256);
    int g3  = (int)((t3 + 255) / 256);
    count_kernel<<<(F3 + 255) / 256, 256, 0, stream>>>(face, F3, deg);
    hist_kernel<<<64, 256, 0, stream>>>(deg, N, hist);
    binscan_kernel<<<1, 256, 0, stream>>>(hist, cursor);
    scatter_kernel<<<gN, 256, 0, stream>>>(deg, N, cursor, perm);
    scan_reduce<<<B, 256, 0, stream>>>(deg, N, partial);
    scan_partials<<<1, 1024, 0, stream>>>(partial, B, indptr + N);
    scan_apply<<<B, 256, 0, stream>>>(deg, N, partial, indptr, ecur);
    fill_kernel<<<(F3 + 255) / 256, 256, 0, stream>>>(face, F, ecur, srcids);

    // layer 1: h = posn (INH=3), OUT=32 — heavy SPLIT=4, light SPLIT=2
    uv_kernel<3, 32><<<gN, 256, 0, stream>>>(posn, posn, W1aT, b1a, u, v, N);
    gather_kernel<32, 4, 2, 4, true><<<g12, 256, 0, stream>>>(
        u, v, perm, indptr, srcids, W1b, b1b, h1, N, HK);
    // layer 2: INH=32, OUT=32
    uv_kernel<32, 32><<<gN, 256, 0, stream>>>(h1, posn, W2aT, b2a, u, v, N);
    gather_kernel<32, 4, 2, 4, true><<<g12, 256, 0, stream>>>(
        u, v, perm, indptr, srcids, W2b, b2b, h2, N, HK);
    // layer 3: INH=32, OUT=64 — heavy SPLIT=8, light SPLIT=4
    uv_kernel<32, 64><<<gN, 256, 0, stream>>>(h2, posn, W3aT, b3a, u, v, N);
    gather_kernel<64, 8, 4, 2, false><<<g3, 256, 0, stream>>>(
        u, v, perm, indptr, srcids, W3b, b3b, h3, N, HK);

    pool_kernel<<<(N + 255) / 256, 256, 0, stream>>>(h3, batch, N, g);
    head_kernel<<<(64 * 41 + 255) / 256, 256, 0, stream>>>(g, Wc, bc, (float*)d_out);
}

// Round 20
// 492.340 us; speedup vs baseline: 1.0332x; 1.0332x over previous
//
#include <hip/hip_runtime.h>

// ---------------------------------------------------------------------------
// PointNet mesh GNN, fp32 — factorized gather, HYBRID lane split, 64-thread
// gather blocks (single-wave blocks -> fine-grained backfill keeps ~20
// waves/CU resident; 256-thread blocks decayed to ~6 and ran latency-bound).
//   hidden preact for edge (src,dst): u[src] - v[dst]
//     u[n] = Wa . [h_n, pos_n] + ba   (per node)
//     v[n] = Wa_pos . pos_n           (per node)
//   message m = relu(u[src]-v[dst]) @ Wb + bb ; h_out[n] = relu(max_e m)
// Nodes in DESCENDING degree order. First HK slots (heaviest ~6%) get 8
// lanes/node; light majority 4. Butterfly max; slice write with STATIC
// register indices; v-row hoisted to registers for OUT=32 layers.
// ---------------------------------------------------------------------------

__global__ __launch_bounds__(256) void prep_kernel(
    const float* __restrict__ pos, float* __restrict__ posn, int N,
    const float* __restrict__ W1a, const float* __restrict__ W2a,
    const float* __restrict__ W3a,
    float* __restrict__ W1aT, float* __restrict__ W2aT, float* __restrict__ W3aT)
{
    int idx = blockIdx.x * blockDim.x + threadIdx.x;
    if (idx < N) {
        float x = pos[idx * 3 + 0];
        float y = pos[idx * 3 + 1];
        float z = pos[idx * 3 + 2];
        float s = fmaxf(fabsf(x) + fabsf(y) + fabsf(z), 1e-12f);
        float inv = 1.0f / s;
        posn[idx * 3 + 0] = x * inv;
        posn[idx * 3 + 1] = y * inv;
        posn[idx * 3 + 2] = z * inv;
    }
    if (blockIdx.x == 0) {
        for (int t = threadIdx.x; t < 6 * 32; t += blockDim.x) {
            int i = t / 32, k = t % 32;
            W1aT[k * 6 + i] = W1a[t];
        }
        for (int t = threadIdx.x; t < 35 * 32; t += blockDim.x) {
            int i = t / 32, k = t % 32;
            W2aT[k * 35 + i] = W2a[t];
        }
        for (int t = threadIdx.x; t < 35 * 64; t += blockDim.x) {
            int i = t / 64, k = t % 64;
            W3aT[k * 35 + i] = W3a[t];
        }
    }
}

__global__ __launch_bounds__(256) void count_kernel(
    const int* __restrict__ face, int F3, int* __restrict__ deg)
{
    int t = blockIdx.x * blockDim.x + threadIdx.x;
    if (t < F3) atomicAdd(&deg[face[t]], 2);
}

// LDS-privatized histogram of clamped degrees; 64 blocks grid-stride.
__global__ __launch_bounds__(256) void hist_kernel(
    const int* __restrict__ deg, int N, int* __restrict__ hist)
{
    __shared__ int lh[256];
    lh[threadIdx.x] = 0;
    __syncthreads();
    int stride = gridDim.x * blockDim.x;
    for (int t = blockIdx.x * blockDim.x + threadIdx.x; t < N; t += stride)
        atomicAdd(&lh[min(deg[t], 255)], 1);
    __syncthreads();
    int c = lh[threadIdx.x];
    if (c) atomicAdd(&hist[threadIdx.x], c);
}

// DESCENDING bin layout: cursor[b] = sum of hist[b'] for b' > b.
__global__ __launch_bounds__(256) void binscan_kernel(
    const int* __restrict__ hist, int* __restrict__ cursor)
{
    __shared__ int sh[256];
    int t = threadIdx.x;
    int rt = 255 - t;            // reversed position
    int v = hist[rt];
    sh[t] = v;
    __syncthreads();
    for (int off = 1; off < 256; off <<= 1) {
        int tv = (t >= off) ? sh[t - off] : 0;
        __syncthreads();
        sh[t] += tv;
        __syncthreads();
    }
    cursor[rt] = sh[t] - v;      // exclusive prefix in reversed order
}

// LDS-privatized counting-sort scatter.
__global__ __launch_bounds__(256) void scatter_kernel(
    const int* __restrict__ deg, int N, int* __restrict__ cursor,
    int* __restrict__ perm)
{
    __shared__ int lh[256];
    __shared__ int lbase[256];
    int tid = threadIdx.x;
    lh[tid] = 0;
    __syncthreads();
    int t = blockIdx.x * blockDim.x + tid;
    int b = 0, r = 0;
    bool valid = (t < N);
    if (valid) {
        b = min(deg[t], 255);
        r = atomicAdd(&lh[b], 1);
    }
    __syncthreads();
    int c = lh[tid];
    if (c) lbase[tid] = atomicAdd(&cursor[tid], c);
    __syncthreads();
    if (valid) perm[lbase[b] + r] = t;
}

// ---- 3-phase multi-block exclusive scan of deg -> indptr (+ ecur copy) ----
__global__ __launch_bounds__(256) void scan_reduce(
    const int* __restrict__ val, int N, int* __restrict__ partial)
{
    __shared__ int sh[256];
    int b0 = blockIdx.x * 1024;
    int sum = 0;
    #pragma unroll
    for (int j = 0; j < 4; j++) {
        int idx = b0 + j * 256 + threadIdx.x;
        if (idx < N) sum += val[idx];
    }
    sh[threadIdx.x] = sum;
    __syncthreads();
    for (int off = 128; off > 0; off >>= 1) {
        if (threadIdx.x < off) sh[threadIdx.x] += sh[threadIdx.x + off];
        __syncthreads();
    }
    if (threadIdx.x == 0) partial[blockIdx.x] = sh[0];
}

__global__ __launch_bounds__(1024) void scan_partials(
    int* __restrict__ partial, int B, int* __restrict__ totalp)
{
    __shared__ int sh[1024];
    int t = threadIdx.x;
    int v = (t < B) ? partial[t] : 0;
    sh[t] = v;
    __syncthreads();
    for (int off = 1; off < 1024; off <<= 1) {
        int tv = (t >= off) ? sh[t - off] : 0;
        __syncthreads();
        sh[t] += tv;
        __syncthreads();
    }
    if (t < B) partial[t] = sh[t] - v;   // exclusive
    if (t == 1023) *totalp = sh[1023];
}

__global__ __launch_bounds__(256) void scan_apply(
    const int* __restrict__ val, int N, const int* __restrict__ partial,
    int* __restrict__ out1, int* __restrict__ out2)
{
    __shared__ int sh[256];
    int t = threadIdx.x;
    int i0 = blockIdx.x * 1024 + t * 4;
    int d[4];
    int s = 0;
    #pragma unroll
    for (int j = 0; j < 4; j++) {
        d[j] = (i0 + j < N) ? val[i0 + j] : 0;
        s += d[j];
    }
    sh[t] = s;
    __syncthreads();
    for (int off = 1; off < 256; off <<= 1) {
        int tv = (t >= off) ? sh[t - off] : 0;
        __syncthreads();
        sh[t] += tv;
        __syncthreads();
    }
    int run = partial[blockIdx.x] + sh[t] - s;
    #pragma unroll
    for (int j = 0; j < 4; j++) {
        int idx = i0 + j;
        if (idx < N) {
            out1[idx] = run;
            out2[idx] = run;
        }
        run += d[j];
    }
}

__global__ __launch_bounds__(256) void fill_kernel(
    const int* __restrict__ face, int F, int* __restrict__ cursor,
    int* __restrict__ srcids)
{
    int t = blockIdx.x * blockDim.x + threadIdx.x;
    if (t >= 3 * F) return;
    int r = t / F;
    int f = t - r * F;
    int v = face[t];
    int r1 = r + 1; if (r1 == 3) r1 = 0;
    int r2 = r + 2; if (r2 >= 3) r2 -= 3;
    int a = face[r1 * F + f];
    int b = face[r2 * F + f];
    int base = atomicAdd(&cursor[v], 2);
    srcids[base] = a;
    srcids[base + 1] = b;
}

// Per node: u[n][k] = ba[k] + sum_i [h_n,pos_n][i] * WaT[k][i]
//           v[n][k] = sum_c pos_n[c] * WaT[k][INH+c]
template <int INH, int OUT>
__global__ __launch_bounds__(256) void uv_kernel(
    const float* __restrict__ h, const float* __restrict__ posn,
    const float* __restrict__ WaT, const float* __restrict__ ba,
    float* __restrict__ u, float* __restrict__ v, int N)
{
    constexpr int IN = INH + 3;
    int n = blockIdx.x * blockDim.x + threadIdx.x;
    if (n >= N) return;
    float x[IN];
    if constexpr (INH % 4 == 0) {
        const float4* hp = (const float4*)(h + (size_t)n * INH);
        #pragma unroll
        for (int i4 = 0; i4 < INH / 4; i4++) {
            float4 t = hp[i4];
            x[i4 * 4 + 0] = t.x;
            x[i4 * 4 + 1] = t.y;
            x[i4 * 4 + 2] = t.z;
            x[i4 * 4 + 3] = t.w;
        }
    } else {
        #pragma unroll
        for (int i = 0; i < INH; i++) x[i] = h[(size_t)n * INH + i];
    }
    x[INH + 0] = posn[n * 3 + 0];
    x[INH + 1] = posn[n * 3 + 1];
    x[INH + 2] = posn[n * 3 + 2];

    float4* up = (float4*)(u + (size_t)n * OUT);
    float4* vp = (float4*)(v + (size_t)n * OUT);
    #pragma unroll 2
    for (int k4 = 0; k4 < OUT / 4; k4++) {
        float uu[4], vv[4];
        #pragma unroll
        for (int j = 0; j < 4; j++) {
            int k = k4 * 4 + j;
            float uk = ba[k];
            #pragma unroll
            for (int i = 0; i < IN; i++)
                uk = fmaf(x[i], WaT[k * IN + i], uk);
            uu[j] = uk;
            float vk = x[INH] * WaT[k * IN + INH];
            vk = fmaf(x[INH + 1], WaT[k * IN + INH + 1], vk);
            vk = fmaf(x[INH + 2], WaT[k * IN + INH + 2], vk);
            vv[j] = vk;
        }
        float4 u4; u4.x = uu[0]; u4.y = uu[1]; u4.z = uu[2]; u4.w = uu[3];
        float4 v4; v4.x = vv[0]; v4.y = vv[1]; v4.z = vv[2]; v4.w = vv[3];
        up[k4] = u4;
        vp[k4] = v4;
    }
}

// Shared gather body: SPLIT lanes cooperate on node perm[gslot]; full acc/M
// rows in registers (static indices); butterfly max; slice write.
template <int OUT, int SPLIT, bool VH>
__device__ __forceinline__ void gather_body(
    int gslot, int t,
    const float* __restrict__ u, const float* __restrict__ v,
    const int* __restrict__ perm, const int* __restrict__ indptr,
    const int* __restrict__ srcids, const float* __restrict__ Wb,
    const float* __restrict__ bb, float* __restrict__ hout)
{
    int n = perm[gslot];
    const float4* vp = (const float4*)(v + (size_t)n * OUT);
    int e0 = indptr[n], e1 = indptr[n + 1];

    float vq[VH ? OUT : 1];
    if constexpr (VH) {
        #pragma unroll
        for (int m = 0; m < OUT / 4; m++) {
            float4 x = vp[m];
            vq[4 * m + 0] = x.x;
            vq[4 * m + 1] = x.y;
            vq[4 * m + 2] = x.z;
            vq[4 * m + 3] = x.w;
        }
    }

    float M[OUT];
    #pragma unroll
    for (int o = 0; o < OUT; o++) M[o] = -1e30f;

    for (int e = e0 + t; e < e1; e += SPLIT) {
        int src = srcids[e];
        const float4* up = (const float4*)(u + (size_t)src * OUT);
        float acc[OUT];
        #pragma unroll
        for (int o = 0; o < OUT; o++) acc[o] = 0.0f;
        #pragma unroll 4
        for (int k4 = 0; k4 < OUT / 4; k4++) {
            float4 u4 = up[k4];
            float vx, vy, vz, vw;
            if constexpr (VH) {
                vx = vq[k4 * 4 + 0]; vy = vq[k4 * 4 + 1];
                vz = vq[k4 * 4 + 2]; vw = vq[k4 * 4 + 3];
            } else {
                float4 v4 = vp[k4];
                vx = v4.x; vy = v4.y; vz = v4.z; vw = v4.w;
            }
            float hk;
            hk = fmaxf(u4.x - vx, 0.0f);
            #pragma unroll
            for (int o = 0; o < OUT; o++)
                acc[o] = fmaf(hk, Wb[(k4 * 4 + 0) * OUT + o], acc[o]);
            hk = fmaxf(u4.y - vy, 0.0f);
            #pragma unroll
            for (int o = 0; o < OUT; o++)
                acc[o] = fmaf(hk, Wb[(k4 * 4 + 1) * OUT + o], acc[o]);
            hk = fmaxf(u4.z - vz, 0.0f);
            #pragma unroll
            for (int o = 0; o < OUT; o++)
                acc[o] = fmaf(hk, Wb[(k4 * 4 + 2) * OUT + o], acc[o]);
            hk = fmaxf(u4.w - vw, 0.0f);
            #pragma unroll
            for (int o = 0; o < OUT; o++)
                acc[o] = fmaf(hk, Wb[(k4 * 4 + 3) * OUT + o], acc[o]);
        }
        #pragma unroll
        for (int o = 0; o < OUT; o++) M[o] = fmaxf(M[o], acc[o]);
    }

    // butterfly max across the aligned SPLIT-lane group (static indices)
    #pragma unroll
    for (int m = 1; m < SPLIT; m <<= 1) {
        #pragma unroll
        for (int o = 0; o < OUT; o++)
            M[o] = fmaxf(M[o], __shfl_xor(M[o], m));
    }

    // lane t writes slice t — statically unrolled branch keeps M in regs
    constexpr int CH = OUT / SPLIT;
    #pragma unroll
    for (int tt = 0; tt < SPLIT; tt++) {
        if (t == tt) {
            float* outp = hout + (size_t)n * OUT + tt * CH;
            #pragma unroll
            for (int o4 = 0; o4 < CH / 4; o4++) {
                float4 w;
                w.x = fmaxf(M[tt * CH + o4 * 4 + 0] + bb[tt * CH + o4 * 4 + 0], 0.0f);
                w.y = fmaxf(M[tt * CH + o4 * 4 + 1] + bb[tt * CH + o4 * 4 + 1], 0.0f);
                w.z = fmaxf(M[tt * CH + o4 * 4 + 2] + bb[tt * CH + o4 * 4 + 2], 0.0f);
                w.w = fmaxf(M[tt * CH + o4 * 4 + 3] + bb[tt * CH + o4 * 4 + 3], 0.0f);
                ((float4*)outp)[o4] = w;
            }
        }
    }
}

// Hybrid split, 64-thread (single-wave) blocks for fine-grained backfill.
// First HK slots (heaviest, perm sorted desc) use 8 lanes/node; rest 4.
// HK multiple of 8 -> HK*8 is 64-aligned: range branch is wave-uniform.
template <int OUT, int MINW, bool VH>
__global__ __launch_bounds__(64, MINW) void gather_kernel(
    const float* __restrict__ u, const float* __restrict__ v,
    const int* __restrict__ perm, const int* __restrict__ indptr,
    const int* __restrict__ srcids, const float* __restrict__ Wb,
    const float* __restrict__ bb, float* __restrict__ hout, int N, int HK)
{
    int gt = blockIdx.x * blockDim.x + threadIdx.x;
    int hthreads = HK * 8;
    if (gt < hthreads) {
        int gslot = gt >> 3;
        int t = gt & 7;
        gather_body<OUT, 8, VH>(gslot, t, u, v, perm, indptr, srcids, Wb, bb, hout);
    } else {
        int g2 = gt - hthreads;
        int gslot = HK + (g2 >> 2);
        int t = g2 & 3;
        if (gslot >= N) return;
        gather_body<OUT, 4, VH>(gslot, t, u, v, perm, indptr, srcids, Wb, bb, hout);
    }
}

// Global max pool over sorted batch ids (h3 >= 0, g init 0).
__global__ __launch_bounds__(256) void pool_kernel(
    const float* __restrict__ h3, const int* __restrict__ batch, int N,
    float* __restrict__ g)
{
    int o = threadIdx.x & 63;
    int sub = threadIdx.x >> 6;
    int n0 = blockIdx.x * 256;
    int nend = min(n0 + 256, N);
    int cur = -1;
    float run = 0.0f;
    for (int n = n0 + sub; n < nend; n += 4) {
        int b = batch[n];
        if (b != cur) {
            if (cur >= 0) atomicMax((int*)&g[cur * 64 + o], __float_as_int(run));
            cur = b;
            run = 0.0f;
        }
        run = fmaxf(run, h3[(size_t)n * 64 + o]);
    }
    if (cur >= 0) atomicMax((int*)&g[cur * 64 + o], __float_as_int(run));
}

__global__ __launch_bounds__(256) void head_kernel(
    const float* __restrict__ g, const float* __restrict__ Wc,
    const float* __restrict__ bc, float* __restrict__ out)
{
    int idx = blockIdx.x * blockDim.x + threadIdx.x;
    if (idx >= 64 * 41) return;
    int bg = idx / 41;
    int o = idx - bg * 41;
    float acc = bc[o];
    #pragma unroll 8
    for (int k = 0; k < 64; k++)
        acc = fmaf(g[bg * 64 + k], Wc[k * 41 + o], acc);
    out[idx] = acc;
}

extern "C" void kernel_launch(void* const* d_in, const int* in_sizes, int n_in,
                              void* d_out, int out_size, void* d_ws, size_t ws_size,
                              hipStream_t stream)
{
    const float* pos   = (const float*)d_in[0];
    const int*   batch = (const int*)d_in[1];
    const int*   face  = (const int*)d_in[2];
    const float* W1a = (const float*)d_in[3];
    const float* b1a = (const float*)d_in[4];
    const float* W1b = (const float*)d_in[5];
    const float* b1b = (const float*)d_in[6];
    const float* W2a = (const float*)d_in[7];
    const float* b2a = (const float*)d_in[8];
    const float* W2b = (const float*)d_in[9];
    const float* b2b = (const float*)d_in[10];
    const float* W3a = (const float*)d_in[11];
    const float* b3a = (const float*)d_in[12];
    const float* W3b = (const float*)d_in[13];
    const float* b3b = (const float*)d_in[14];
    const float* Wc  = (const float*)d_in[15];
    const float* bc  = (const float*)d_in[16];

    int N = in_sizes[0] / 3;
    int F = in_sizes[2] / 3;
    int F3 = 3 * F;

    float* ws   = (float*)d_ws;
    float* posn = ws;
    float* W1aT = posn + (size_t)N * 3;
    float* W2aT = W1aT + 6 * 32;
    float* W3aT = W2aT + 35 * 32;
    float* h3   = W3aT + 35 * 64;           // 64N floats; h1 aliases first 32N
    float* h1   = h3;                        // dead before gather3 writes h3
    float* h2   = h3 + (size_t)N * 64;       // 32N
    float* u    = h2 + (size_t)N * 32;       // 64N
    float* v    = u + (size_t)N * 64;        // 64N
    float* g    = v + (size_t)N * 64;        // 4096
    int* deg    = (int*)(g + 64 * 64);       // N (read-only after count)
    int* indptr = deg + N;                   // N+1
    int* srcids = indptr + (N + 1);          // 6F
    int* perm   = srcids + (size_t)6 * F;    // N
    int* hist   = perm + N;                  // 256
    int* cursor = hist + 256;                // 256
    int* ecur   = cursor + 256;              // N (fill cursor)
    int* partial = ecur + N;                 // ceil(N/1024)

    hipMemsetAsync(deg, 0, (size_t)N * sizeof(int), stream);
    hipMemsetAsync(hist, 0, 256 * sizeof(int), stream);
    hipMemsetAsync(g, 0, 64 * 64 * sizeof(float), stream);

    prep_kernel<<<(N + 255) / 256, 256, 0, stream>>>(
        pos, posn, N, W1a, W2a, W3a, W1aT, W2aT, W3aT);

    int gN = (N + 255) / 256;
    int B = (N + 1023) / 1024;
    int HK = ((N / 16) + 7) & ~7;            // heavy slot count, 8-aligned
    if (HK > N) HK = N & ~7;
    size_t gthreads = (size_t)HK * 8 + (size_t)(N - HK) * 4;
    int gG = (int)((gthreads + 63) / 64);
    count_kernel<<<(F3 + 255) / 256, 256, 0, stream>>>(face, F3, deg);
    hist_kernel<<<64, 256, 0, stream>>>(deg, N, hist);
    binscan_kernel<<<1, 256, 0, stream>>>(hist, cursor);
    scatter_kernel<<<gN, 256, 0, stream>>>(deg, N, cursor, perm);
    scan_reduce<<<B, 256, 0, stream>>>(deg, N, partial);
    scan_partials<<<1, 1024, 0, stream>>>(partial, B, indptr + N);
    scan_apply<<<B, 256, 0, stream>>>(deg, N, partial, indptr, ecur);
    fill_kernel<<<(F3 + 255) / 256, 256, 0, stream>>>(face, F, ecur, srcids);

    // layer 1: h = posn (INH=3), OUT=32
    uv_kernel<3, 32><<<gN, 256, 0, stream>>>(posn, posn, W1aT, b1a, u, v, N);
    gather_kernel<32, 4, true><<<gG, 64, 0, stream>>>(
        u, v, perm, indptr, srcids, W1b, b1b, h1, N, HK);
    // layer 2: INH=32, OUT=32
    uv_kernel<32, 32><<<gN, 256, 0, stream>>>(h1, posn, W2aT, b2a, u, v, N);
    gather_kernel<32, 4, true><<<gG, 64, 0, stream>>>(
        u, v, perm, indptr, srcids, W2b, b2b, h2, N, HK);
    // layer 3: INH=32, OUT=64
    uv_kernel<32, 64><<<gN, 256, 0, stream>>>(h2, posn, W3aT, b3a, u, v, N);
    gather_kernel<64, 2, false><<<gG, 64, 0, stream>>>(
        u, v, perm, indptr, srcids, W3b, b3b, h3, N, HK);

    pool_kernel<<<(N + 255) / 256, 256, 0, stream>>>(h3, batch, N, g);
    head_kernel<<<(64 * 41 + 255) / 256, 256, 0, stream>>>(g, Wc, bc, (float*)d_out);
}